// Round 3
// baseline (490.592 us; speedup 1.0000x reference)
//
#include <hip/hip_runtime.h>
#include <hip/hip_bf16.h>

#define B_SZ 512
#define L_SZ 70
#define D_SZ 128
#define NCOL 99999          // output columns = emb rows 1..99999
#define M_ROWS (B_SZ * L_SZ) // 35840

typedef __attribute__((ext_vector_type(4))) float f32x4;
typedef __attribute__((ext_vector_type(8))) short bf16x8;

static __device__ __forceinline__ short f2bf(float x) {
    union { float f; unsigned u; } v; v.f = x;
    unsigned r = v.u + 0x7fffu + ((v.u >> 16) & 1u);  // RNE
    return (short)(r >> 16);
}
static __device__ __forceinline__ float bf2f(unsigned short h) {
    union { unsigned u; float f; } v; v.u = ((unsigned)h) << 16; return v.f;
}

// ---- convert weights to bf16 (Wkv = attn_in_w rows 128..383; W2 = w_two) ----
__global__ void k_prep_w(const float* attn_in_w, const float* w_two,
                         short* Wkv, short* W2) {
    int i = blockIdx.x * 256 + threadIdx.x;
    if (i < 256 * 128) Wkv[i] = f2bf(attn_in_w[128 * 128 + i]);
    if (i < 128 * 128) W2[i] = f2bf(w_two[i]);
}

// ---- per batch: last_idx, ht0, qp = s @ wq.T + bq ----
__global__ void k_ht0_qp(const float* hidden, const int* mask, const float* s,
                         const float* attn_in_w, const float* attn_in_b,
                         float* ht0, float* qp) {
    int b = blockIdx.x, t = threadIdx.x;
    __shared__ float s_sh[128];
    __shared__ int idx_sh;
    if (t < 64) {
        int acc = 0;
        for (int l = t; l < L_SZ; l += 64) acc += mask[b * L_SZ + l];
        for (int off = 32; off; off >>= 1) acc += __shfl_down(acc, off);
        if (t == 0) {
            int idx = acc - 1;
            if (idx < 0) idx = 0;
            if (idx > L_SZ - 1) idx = L_SZ - 1;
            idx_sh = idx;
        }
    }
    s_sh[t] = s[b * 128 + t];
    __syncthreads();
    int idx = idx_sh;
    ht0[b * 128 + t] = hidden[(b * L_SZ + idx) * 128 + t];
    float acc = attn_in_b[t];
    const float* wq = attn_in_w + t * 128;
    for (int k = 0; k < 128; k++) acc += s_sh[k] * wq[k];
    qp[b * 128 + t] = acc;
}

// ---- gate: sigma = sigmoid([h0,h] . w_gate); g = h0*sig + h*(1-sig) (bf16) ----
__global__ void k_gate(const float* hidden, const float* hidden0,
                       const float* w_gate, short* g_bf) {
    int row = blockIdx.x, t = threadIdx.x;
    float h0 = hidden0[row * 128 + t], h = hidden[row * 128 + t];
    float p = h0 * w_gate[t] + h * w_gate[128 + t];
    for (int off = 32; off; off >>= 1) p += __shfl_down(p, off);
    __shared__ float part[2];
    __shared__ float sig_sh;
    if ((t & 63) == 0) part[t >> 6] = p;
    __syncthreads();
    if (t == 0) {
        float tot = part[0] + part[1];
        sig_sh = 1.f / (1.f + __expf(-tot));
    }
    __syncthreads();
    float sg = sig_sh;
    g_bf[row * 128 + t] = f2bf(h0 * sg + h * (1.f - sg));
}

// ---- kv = hidden @ [wk;wv].T + [bk;bv]   (M=35840, N=256, K=128) ----
__global__ void k_gemm_kv(const float* hidden, const short* Wkv,
                          const float* attn_in_b, short* kv) {
    int lane = threadIdx.x & 63, w = threadIdx.x >> 6;
    int r0 = blockIdx.x * 64 + w * 16;
    int ar = r0 + (lane & 15);
    int kbase = (lane >> 4) * 8;
    bf16x8 aF[4];
    const float* Arow = hidden + ar * 128 + kbase;
    for (int kk = 0; kk < 4; kk++) {
        float4 x0 = *(const float4*)(Arow + kk * 32);
        float4 x1 = *(const float4*)(Arow + kk * 32 + 4);
        bf16x8 f;
        f[0] = f2bf(x0.x); f[1] = f2bf(x0.y); f[2] = f2bf(x0.z); f[3] = f2bf(x0.w);
        f[4] = f2bf(x1.x); f[5] = f2bf(x1.y); f[6] = f2bf(x1.z); f[7] = f2bf(x1.w);
        aF[kk] = f;
    }
    int cl = lane & 15;
    int rowbase = r0 + (lane >> 4) * 4;
    for (int ct = 0; ct < 16; ct++) {
        int c = ct * 16 + cl;
        f32x4 acc = {0.f, 0.f, 0.f, 0.f};
        const short* Brow = Wkv + c * 128 + kbase;
        for (int kk = 0; kk < 4; kk++) {
            bf16x8 bF = *(const bf16x8*)(Brow + kk * 32);
            acc = __builtin_amdgcn_mfma_f32_16x16x32_bf16(aF[kk], bF, acc, 0, 0, 0);
        }
        float bias = attn_in_b[128 + c];
        for (int rg = 0; rg < 4; rg++)
            kv[(rowbase + rg) * 256 + c] = f2bf(acc[rg] + bias);
    }
}

// ---- fused MHA (1 query) + q01 = (ht@w_one.T+b_one) + (ht0@w_zero.T+b_zero) ----
__global__ void k_attn(const short* kv, const float* qp, const float* ht0,
                       const float* attn_out_w, const float* attn_out_b,
                       const float* w_zero, const float* b_zero,
                       const float* w_one, const float* b_one, float* q01) {
    int b = blockIdx.x, t = threadIdx.x;
    __shared__ float kp_s[L_SZ][128];
    __shared__ float qp_s[128];
    __shared__ float sc[8][72];
    __shared__ float o_s[128];
    __shared__ float ht_s[128];
    __shared__ float ht0_s[128];
    qp_s[t] = qp[b * 128 + t];
    ht0_s[t] = ht0[b * 128 + t];
    const unsigned short* kvrow = (const unsigned short*)kv + b * L_SZ * 256;
    for (int i = t; i < L_SZ * 128; i += 128) {
        int l = i >> 7, d = i & 127;
        kp_s[l][d] = bf2f(kvrow[l * 256 + d]);
    }
    __syncthreads();
    for (int task = t; task < 8 * L_SZ; task += 128) {
        int h = task / L_SZ, l = task % L_SZ;
        float acc = 0.f;
        for (int j = 0; j < 16; j++) acc += qp_s[h * 16 + j] * kp_s[l][h * 16 + j];
        sc[h][l] = acc * 0.25f;  // 1/sqrt(16)
    }
    __syncthreads();
    if (t < 8) {
        float m = -1e30f;
        for (int l = 0; l < L_SZ; l++) m = fmaxf(m, sc[t][l]);
        float ssum = 0.f;
        for (int l = 0; l < L_SZ; l++) { float e = __expf(sc[t][l] - m); sc[t][l] = e; ssum += e; }
        float inv = 1.f / ssum;
        for (int l = 0; l < L_SZ; l++) sc[t][l] *= inv;
    }
    __syncthreads();
    {
        int h = t >> 4;
        float acc = 0.f;
        for (int l = 0; l < L_SZ; l++) acc += sc[h][l] * bf2f(kvrow[l * 256 + 128 + t]);
        o_s[t] = acc;
    }
    __syncthreads();
    {
        float acc = attn_out_b[t];
        const float* wr = attn_out_w + t * 128;
        for (int k = 0; k < 128; k++) acc += o_s[k] * wr[k];
        ht_s[t] = acc;
    }
    __syncthreads();
    {
        float acc = b_one[t] + b_zero[t];
        const float* w1 = w_one + t * 128;
        const float* w0 = w_zero + t * 128;
        for (int k = 0; k < 128; k++) acc += ht_s[k] * w1[k] + ht0_s[k] * w0[k];
        q01[b * 128 + t] = acc;
    }
}

// ---- q2 GEMM + fused alpha-logit epilogue:
// alpha[b,l,h] = sum_d sigmoid(q2[b,l,d] + q01[b,d]) * w_three[h,d] ----
__global__ void k_gemm_q2_alpha(const short* g_bf, const short* W2, const float* b_two,
                                const float* q01, const float* w_three, float* alphaL) {
    int lane = threadIdx.x & 63, w = threadIdx.x >> 6;
    int r0 = blockIdx.x * 64 + w * 16;
    int ar = r0 + (lane & 15);
    int kbase = (lane >> 4) * 8;
    bf16x8 aF[4];
    const short* Arow = g_bf + ar * 128 + kbase;
    for (int kk = 0; kk < 4; kk++) aF[kk] = *(const bf16x8*)(Arow + kk * 32);
    float part[4][8];
    for (int r = 0; r < 4; r++)
        for (int h = 0; h < 8; h++) part[r][h] = 0.f;
    int cl = lane & 15;
    int rowbase = r0 + (lane >> 4) * 4;
    for (int ct = 0; ct < 8; ct++) {
        int c = ct * 16 + cl;
        f32x4 acc = {0.f, 0.f, 0.f, 0.f};
        const short* Brow = W2 + c * 128 + kbase;
        for (int kk = 0; kk < 4; kk++) {
            bf16x8 bF = *(const bf16x8*)(Brow + kk * 32);
            acc = __builtin_amdgcn_mfma_f32_16x16x32_bf16(aF[kk], bF, acc, 0, 0, 0);
        }
        float bias = b_two[c];
        for (int rg = 0; rg < 4; rg++) {
            int row = rowbase + rg;
            int bb = row / L_SZ;
            float val = acc[rg] + bias + q01[bb * 128 + c];
            float sg = 1.f / (1.f + __expf(-val));
            for (int h = 0; h < 8; h++) part[rg][h] += sg * w_three[h * 128 + c];
        }
    }
    for (int off = 1; off < 16; off <<= 1)
        for (int rg = 0; rg < 4; rg++)
            for (int h = 0; h < 8; h++)
                part[rg][h] += __shfl_xor(part[rg][h], off);
    if ((lane & 15) == 0) {
        for (int rg = 0; rg < 4; rg++) {
            int row = rowbase + rg;
            for (int h = 0; h < 8; h++) alphaL[row * 8 + h] = part[rg][h];
        }
    }
}

// ---- alpha softmax over L (masked) + pooling + w_trans + row-normalize ----
__global__ void k_alpha_a(const float* alphaL, const int* mask, const short* g_bf,
                          const float* ht0, const float* w_trans, const float* b_trans,
                          short* a_bf) {
    int b = blockIdx.x, t = threadIdx.x;
    __shared__ float aw[L_SZ][8];
    __shared__ float mf[L_SZ];
    __shared__ float a_s[128];
    __shared__ float ht0_s[128];
    __shared__ float red[2];
    for (int i = t; i < L_SZ; i += 128) mf[i] = (float)mask[b * L_SZ + i];
    for (int i = t; i < L_SZ * 8; i += 128) aw[i >> 3][i & 7] = alphaL[b * L_SZ * 8 + i];
    ht0_s[t] = ht0[b * 128 + t];
    __syncthreads();
    if (t < 8) {
        float m = -1e30f;
        for (int l = 0; l < L_SZ; l++) {
            float v = (mf[l] == 0.f) ? -1e30f : aw[l][t];
            if (v > m) m = v;
        }
        float ssum = 0.f;
        for (int l = 0; l < L_SZ; l++) {
            float v = (mf[l] == 0.f) ? -1e30f : aw[l][t];
            float e = __expf(v - m);
            ssum += e; aw[l][t] = e;
        }
        float inv = 1.f / ssum;
        for (int l = 0; l < L_SZ; l++) aw[l][t] *= inv;
    }
    __syncthreads();
    int h = t >> 4;
    float acc = 0.f;
    const unsigned short* grow = (const unsigned short*)g_bf + b * L_SZ * 128 + t;
    for (int l = 0; l < L_SZ; l++) acc += aw[l][h] * bf2f(grow[l * 128]) * mf[l];
    a_s[t] = acc;
    __syncthreads();
    float a2 = b_trans[t];
    const float* wt = w_trans + t * 256;
    for (int k = 0; k < 128; k++) a2 += a_s[k] * wt[k] + ht0_s[k] * wt[128 + k];
    float sq = a2 * a2;
    for (int off = 32; off; off >>= 1) sq += __shfl_down(sq, off);
    if ((t & 63) == 0) red[t >> 6] = sq;
    __syncthreads();
    float nrm = sqrtf(red[0] + red[1]) + 1e-12f;
    a_bf[b * 128 + t] = f2bf(a2 / nrm);
}

// ---- normalize emb rows 1..99999 -> bf16 ----
__global__ void k_embnorm(const float* emb, short* bn) {
    int w = threadIdx.x >> 6, lane = threadIdx.x & 63;
    int row = blockIdx.x * 4 + w;
    if (row >= NCOL) return;
    const float* e = emb + (row + 1) * 128;
    float x0 = e[lane], x1 = e[lane + 64];
    float sq = x0 * x0 + x1 * x1;
    for (int off = 32; off; off >>= 1) sq += __shfl_xor(sq, off);
    float inv = 1.f / (sqrtf(sq) + 1e-12f);
    bn[row * 128 + lane] = f2bf(x0 * inv);
    bn[row * 128 + lane + 64] = f2bf(x1 * inv);
}

// ---- final: out = 12 * a_norm @ b_norm.T   (M=512, N=99999, K=128) ----
__global__ void k_final(const short* a_bf, const short* bn, float* out) {
    int lane = threadIdx.x & 63, w = threadIdx.x >> 6;
    int wr = w >> 1, wc = w & 1;
    int rbase = blockIdx.y * 128 + wr * 64;
    int cbase = blockIdx.x * 128 + wc * 64;
    int kbase = (lane >> 4) * 8;
    int rl = lane & 15;
    bf16x8 aF[4][4];
    for (int rt = 0; rt < 4; rt++) {
        const short* Arow = a_bf + (rbase + rt * 16 + rl) * 128 + kbase;
        for (int kk = 0; kk < 4; kk++) aF[rt][kk] = *(const bf16x8*)(Arow + kk * 32);
    }
    f32x4 acc[4][4];
    for (int rt = 0; rt < 4; rt++)
        for (int ct = 0; ct < 4; ct++) acc[rt][ct] = (f32x4){0.f, 0.f, 0.f, 0.f};
    for (int ct = 0; ct < 4; ct++) {
        int c = cbase + ct * 16 + rl;
        bf16x8 bF[4];
        if (c < NCOL) {
            const short* Brow = bn + (long)c * 128 + kbase;
            for (int kk = 0; kk < 4; kk++) bF[kk] = *(const bf16x8*)(Brow + kk * 32);
        } else {
            for (int kk = 0; kk < 4; kk++) bF[kk] = (bf16x8){0, 0, 0, 0, 0, 0, 0, 0};
        }
        for (int kk = 0; kk < 4; kk++)
            for (int rt = 0; rt < 4; rt++)
                acc[rt][ct] = __builtin_amdgcn_mfma_f32_16x16x32_bf16(aF[rt][kk], bF[kk], acc[rt][ct], 0, 0, 0);
    }
    int rowoff = (lane >> 4) * 4;
    for (int rt = 0; rt < 4; rt++) {
        int r = rbase + rt * 16 + rowoff;
        for (int ct = 0; ct < 4; ct++) {
            int c = cbase + ct * 16 + rl;
            if (c >= NCOL) continue;
            for (int rg = 0; rg < 4; rg++)
                out[(long)(r + rg) * NCOL + c] = 12.f * acc[rt][ct][rg];
        }
    }
}

extern "C" void kernel_launch(void* const* d_in, const int* in_sizes, int n_in,
                              void* d_out, int out_size, void* d_ws, size_t ws_size,
                              hipStream_t stream) {
    const float* hidden     = (const float*)d_in[0];
    const float* hidden0    = (const float*)d_in[1];
    const int*   mask       = (const int*)d_in[2];
    const float* s          = (const float*)d_in[3];
    const float* emb        = (const float*)d_in[4];
    const float* attn_in_w  = (const float*)d_in[5];
    const float* attn_in_b  = (const float*)d_in[6];
    const float* attn_out_w = (const float*)d_in[7];
    const float* attn_out_b = (const float*)d_in[8];
    const float* w_zero     = (const float*)d_in[9];
    const float* b_zero     = (const float*)d_in[10];
    const float* w_one      = (const float*)d_in[11];
    const float* b_one      = (const float*)d_in[12];
    const float* w_two      = (const float*)d_in[13];
    const float* b_two      = (const float*)d_in[14];
    const float* w_three    = (const float*)d_in[15];
    const float* w_gate     = (const float*)d_in[16];
    const float* w_trans    = (const float*)d_in[17];
    const float* b_trans    = (const float*)d_in[18];
    float* out = (float*)d_out;

    char* p = (char*)d_ws;
    float* ht0    = (float*)p; p += (size_t)B_SZ * 128 * 4;
    float* qp     = (float*)p; p += (size_t)B_SZ * 128 * 4;
    float* q01    = (float*)p; p += (size_t)B_SZ * 128 * 4;
    float* alphaL = (float*)p; p += (size_t)B_SZ * L_SZ * 8 * 4;
    short* a_bf   = (short*)p; p += (size_t)B_SZ * 128 * 2;
    short* Wkv    = (short*)p; p += (size_t)256 * 128 * 2;
    short* W2     = (short*)p; p += (size_t)128 * 128 * 2;
    short* g_bf   = (short*)p; p += (size_t)M_ROWS * 128 * 2;
    short* kv     = (short*)p; p += (size_t)M_ROWS * 256 * 2;
    short* bn     = (short*)p; p += (size_t)NCOL * 128 * 2;

    k_prep_w<<<128, 256, 0, stream>>>(attn_in_w, w_two, Wkv, W2);
    k_ht0_qp<<<B_SZ, 128, 0, stream>>>(hidden, mask, s, attn_in_w, attn_in_b, ht0, qp);
    k_gate<<<M_ROWS, 128, 0, stream>>>(hidden, hidden0, w_gate, g_bf);
    k_gemm_kv<<<M_ROWS / 64, 256, 0, stream>>>(hidden, Wkv, attn_in_b, kv);
    k_attn<<<B_SZ, 128, 0, stream>>>(kv, qp, ht0, attn_out_w, attn_out_b,
                                     w_zero, b_zero, w_one, b_one, q01);
    k_gemm_q2_alpha<<<M_ROWS / 64, 256, 0, stream>>>(g_bf, W2, b_two, q01, w_three, alphaL);
    k_alpha_a<<<B_SZ, 128, 0, stream>>>(alphaL, mask, g_bf, ht0, w_trans, b_trans, a_bf);
    k_embnorm<<<(NCOL + 3) / 4, 256, 0, stream>>>(emb, bn);
    k_final<<<dim3((NCOL + 127) / 128, 4), 256, 0, stream>>>(a_bf, bn, out);
}

// Round 5
// 459.550 us; speedup vs baseline: 1.0675x; 1.0675x over previous
//
#include <hip/hip_runtime.h>
#include <hip/hip_bf16.h>

#define B_SZ 512
#define L_SZ 70
#define D_SZ 128
#define NCOL 99999           // output columns = emb rows 1..99999
#define M_ROWS (B_SZ * L_SZ) // 35840

typedef __attribute__((ext_vector_type(4))) float f32x4;
typedef __attribute__((ext_vector_type(8))) short bf16x8;

static __device__ __forceinline__ short f2bf(float x) {
    union { float f; unsigned u; } v; v.f = x;
    unsigned r = v.u + 0x7fffu + ((v.u >> 16) & 1u);  // RNE
    return (short)(r >> 16);
}
static __device__ __forceinline__ float bf2f(unsigned short h) {
    union { unsigned u; float f; } v; v.u = ((unsigned)h) << 16; return v.f;
}

// ---- prep: bf16 weights + fp32 transposed weights for coalesced matvecs ----
__global__ void k_prep(const float* attn_in_w, const float* w_two,
                       const float* attn_out_w, const float* w_zero,
                       const float* w_one, const float* w_trans,
                       short* Wkv, short* W2,
                       float* wqT, float* woT, float* w0T, float* w1T, float* wtT) {
    int i = blockIdx.x * 256 + threadIdx.x;   // 0 .. 32767
    if (i < 256 * 128) Wkv[i] = f2bf(attn_in_w[128 * 128 + i]);
    if (i < 128 * 128) {
        W2[i] = f2bf(w_two[i]);
        int r = i >> 7, c = i & 127;
        wqT[c * 128 + r] = attn_in_w[i];
        woT[c * 128 + r] = attn_out_w[i];
        w0T[c * 128 + r] = w_zero[i];
        w1T[c * 128 + r] = w_one[i];
    }
    if (i < 128 * 256) {                      // w_trans [128][256] -> wtT [256][128]
        int r = i >> 8, c = i & 255;
        wtT[c * 128 + r] = w_trans[i];
    }
}

// ---- gate: sigma = sigmoid([h0,h] . w_gate); g = h0*sig + h*(1-sig) (bf16) ----
__global__ void k_gate(const float* hidden, const float* hidden0,
                       const float* w_gate, short* g_bf) {
    int row = blockIdx.x, t = threadIdx.x;
    float h0 = hidden0[row * 128 + t], h = hidden[row * 128 + t];
    float p = h0 * w_gate[t] + h * w_gate[128 + t];
    for (int off = 32; off; off >>= 1) p += __shfl_down(p, off);
    __shared__ float part[2];
    __shared__ float sig_sh;
    if ((t & 63) == 0) part[t >> 6] = p;
    __syncthreads();
    if (t == 0) {
        float tot = part[0] + part[1];
        sig_sh = 1.f / (1.f + __expf(-tot));
    }
    __syncthreads();
    float sg = sig_sh;
    g_bf[row * 128 + t] = f2bf(h0 * sg + h * (1.f - sg));
}

// ---- kv = hidden @ [wk;wv].T + [bk;bv]   (M=35840, N=256, K=128) ----
__global__ void k_gemm_kv(const float* hidden, const short* Wkv,
                          const float* attn_in_b, short* kv) {
    int lane = threadIdx.x & 63, w = threadIdx.x >> 6;
    int r0 = blockIdx.x * 64 + w * 16;
    int ar = r0 + (lane & 15);
    int kbase = (lane >> 4) * 8;
    bf16x8 aF[4];
    const float* Arow = hidden + ar * 128 + kbase;
    for (int kk = 0; kk < 4; kk++) {
        float4 x0 = *(const float4*)(Arow + kk * 32);
        float4 x1 = *(const float4*)(Arow + kk * 32 + 4);
        bf16x8 f;
        f[0] = f2bf(x0.x); f[1] = f2bf(x0.y); f[2] = f2bf(x0.z); f[3] = f2bf(x0.w);
        f[4] = f2bf(x1.x); f[5] = f2bf(x1.y); f[6] = f2bf(x1.z); f[7] = f2bf(x1.w);
        aF[kk] = f;
    }
    int cl = lane & 15;
    int rowbase = r0 + (lane >> 4) * 4;
    for (int ct = 0; ct < 16; ct++) {
        int c = ct * 16 + cl;
        f32x4 acc = {0.f, 0.f, 0.f, 0.f};
        const short* Brow = Wkv + c * 128 + kbase;
        for (int kk = 0; kk < 4; kk++) {
            bf16x8 bF = *(const bf16x8*)(Brow + kk * 32);
            acc = __builtin_amdgcn_mfma_f32_16x16x32_bf16(aF[kk], bF, acc, 0, 0, 0);
        }
        float bias = attn_in_b[128 + c];
        for (int rg = 0; rg < 4; rg++)
            kv[(rowbase + rg) * 256 + c] = f2bf(acc[rg] + bias);
    }
}

// ---- fused: last_idx/ht0/qp + MHA (1 query) + q01 matvecs ----
__global__ void k_attn(const float* hidden, const int* mask, const float* s,
                       const float* wqT, const float* attn_in_b,
                       const short* kv,
                       const float* woT, const float* attn_out_b,
                       const float* w0T, const float* b_zero,
                       const float* w1T, const float* b_one,
                       float* ht0, float* q01) {
    int b = blockIdx.x, t = threadIdx.x;
    __shared__ float kp_s[L_SZ][128];
    __shared__ float s_sh[128], qp_s[128], o_s[128], ht_s[128], ht0_s[128];
    __shared__ float sc[8][72];
    __shared__ int idx_sh;
    if (t < 64) {
        int acc = 0;
        for (int l = t; l < L_SZ; l += 64) acc += mask[b * L_SZ + l];
        for (int off = 32; off; off >>= 1) acc += __shfl_down(acc, off);
        if (t == 0) {
            int idx = acc - 1;
            if (idx < 0) idx = 0;
            if (idx > L_SZ - 1) idx = L_SZ - 1;
            idx_sh = idx;
        }
    }
    s_sh[t] = s[b * 128 + t];
    const unsigned short* kvrow = (const unsigned short*)kv + (size_t)b * L_SZ * 256;
    for (int i = t; i < L_SZ * 128; i += 128) {
        int l = i >> 7, d = i & 127;
        kp_s[l][d] = bf2f(kvrow[l * 256 + d]);
    }
    __syncthreads();
    {
        float h0 = hidden[((size_t)b * L_SZ + idx_sh) * 128 + t];
        ht0[b * 128 + t] = h0;
        ht0_s[t] = h0;
        float acc = attn_in_b[t];
        for (int k = 0; k < 128; k++) acc += s_sh[k] * wqT[k * 128 + t];
        qp_s[t] = acc;
    }
    __syncthreads();
    for (int task = t; task < 8 * L_SZ; task += 128) {
        int h = task / L_SZ, l = task % L_SZ;
        float acc = 0.f;
        for (int j = 0; j < 16; j++) acc += qp_s[h * 16 + j] * kp_s[l][h * 16 + j];
        sc[h][l] = acc * 0.25f;  // 1/sqrt(16)
    }
    __syncthreads();
    if (t < 8) {
        float m = -1e30f;
        for (int l = 0; l < L_SZ; l++) m = fmaxf(m, sc[t][l]);
        float ssum = 0.f;
        for (int l = 0; l < L_SZ; l++) { float e = __expf(sc[t][l] - m); sc[t][l] = e; ssum += e; }
        float inv = 1.f / ssum;
        for (int l = 0; l < L_SZ; l++) sc[t][l] *= inv;
    }
    __syncthreads();
    {
        int h = t >> 4;
        float acc = 0.f;
        for (int l = 0; l < L_SZ; l++) acc += sc[h][l] * bf2f(kvrow[l * 256 + 128 + t]);
        o_s[t] = acc;
    }
    __syncthreads();
    {
        float acc = attn_out_b[t];
        for (int k = 0; k < 128; k++) acc += o_s[k] * woT[k * 128 + t];
        ht_s[t] = acc;
    }
    __syncthreads();
    {
        float acc = b_one[t] + b_zero[t];
        for (int k = 0; k < 128; k++) acc += ht_s[k] * w1T[k * 128 + t] + ht0_s[k] * w0T[k * 128 + t];
        q01[b * 128 + t] = acc;
    }
}

// ---- q2 GEMM + fused alpha-logit epilogue ----
__global__ void k_gemm_q2_alpha(const short* g_bf, const short* W2, const float* b_two,
                                const float* q01, const float* w_three, float* alphaL) {
    int lane = threadIdx.x & 63, w = threadIdx.x >> 6;
    int r0 = blockIdx.x * 64 + w * 16;
    int ar = r0 + (lane & 15);
    int kbase = (lane >> 4) * 8;
    bf16x8 aF[4];
    const short* Arow = g_bf + ar * 128 + kbase;
    for (int kk = 0; kk < 4; kk++) aF[kk] = *(const bf16x8*)(Arow + kk * 32);
    float part[4][8];
    for (int r = 0; r < 4; r++)
        for (int h = 0; h < 8; h++) part[r][h] = 0.f;
    int cl = lane & 15;
    int rowbase = r0 + (lane >> 4) * 4;
    for (int ct = 0; ct < 8; ct++) {
        int c = ct * 16 + cl;
        f32x4 acc = {0.f, 0.f, 0.f, 0.f};
        const short* Brow = W2 + c * 128 + kbase;
        for (int kk = 0; kk < 4; kk++) {
            bf16x8 bF = *(const bf16x8*)(Brow + kk * 32);
            acc = __builtin_amdgcn_mfma_f32_16x16x32_bf16(aF[kk], bF, acc, 0, 0, 0);
        }
        float bias = b_two[c];
        for (int rg = 0; rg < 4; rg++) {
            int row = rowbase + rg;
            int bb = row / L_SZ;
            float val = acc[rg] + bias + q01[bb * 128 + c];
            float sg = 1.f / (1.f + __expf(-val));
            for (int h = 0; h < 8; h++) part[rg][h] += sg * w_three[h * 128 + c];
        }
    }
    for (int off = 1; off < 16; off <<= 1)
        for (int rg = 0; rg < 4; rg++)
            for (int h = 0; h < 8; h++)
                part[rg][h] += __shfl_xor(part[rg][h], off);
    if ((lane & 15) == 0) {
        for (int rg = 0; rg < 4; rg++) {
            int row = rowbase + rg;
            for (int h = 0; h < 8; h++) alphaL[row * 8 + h] = part[rg][h];
        }
    }
}

// ---- alpha softmax over L (masked) + pooling + w_trans + row-normalize ----
__global__ void k_alpha_a(const float* alphaL, const int* mask, const short* g_bf,
                          const float* ht0, const float* wtT, const float* b_trans,
                          short* a_bf) {
    int b = blockIdx.x, t = threadIdx.x;
    __shared__ float aw[L_SZ][8];
    __shared__ float mf[L_SZ];
    __shared__ float a_s[128];
    __shared__ float ht0_s[128];
    __shared__ float red[2];
    for (int i = t; i < L_SZ; i += 128) mf[i] = (float)mask[b * L_SZ + i];
    for (int i = t; i < L_SZ * 8; i += 128) aw[i >> 3][i & 7] = alphaL[b * L_SZ * 8 + i];
    ht0_s[t] = ht0[b * 128 + t];
    __syncthreads();
    if (t < 8) {
        float m = -1e30f;
        for (int l = 0; l < L_SZ; l++) {
            float v = (mf[l] == 0.f) ? -1e30f : aw[l][t];
            if (v > m) m = v;
        }
        float ssum = 0.f;
        for (int l = 0; l < L_SZ; l++) {
            float v = (mf[l] == 0.f) ? -1e30f : aw[l][t];
            float e = __expf(v - m);
            ssum += e; aw[l][t] = e;
        }
        float inv = 1.f / ssum;
        for (int l = 0; l < L_SZ; l++) aw[l][t] *= inv;
    }
    __syncthreads();
    int h = t >> 4;
    float acc = 0.f;
    const unsigned short* grow = (const unsigned short*)g_bf + b * L_SZ * 128 + t;
    for (int l = 0; l < L_SZ; l++) acc += aw[l][h] * bf2f(grow[l * 128]) * mf[l];
    a_s[t] = acc;
    __syncthreads();
    float a2 = b_trans[t];
    for (int k = 0; k < 128; k++)
        a2 += a_s[k] * wtT[k * 128 + t] + ht0_s[k] * wtT[(128 + k) * 128 + t];
    float sq = a2 * a2;
    for (int off = 32; off; off >>= 1) sq += __shfl_down(sq, off);
    if ((t & 63) == 0) red[t >> 6] = sq;
    __syncthreads();
    float nrm = sqrtf(red[0] + red[1]) + 1e-12f;
    a_bf[b * 128 + t] = f2bf(a2 / nrm);
}

// ---- final: out = 12 * a_norm @ (emb[1:]/||.||).T   (M=512, N=99999, K=128)
// Fused emb normalization; B register-resident (each wave owns 32 cols);
// loop over all 32 row-tiles; LDS-staged coalesced stores (256B segments).
__global__ void __launch_bounds__(256, 4) k_final(const short* a_bf, const float* emb, float* out) {
    __shared__ float lds_c[16][132];   // stride 132: 2-way max bank aliasing
    int t = threadIdx.x;
    int lane = t & 63, w = t >> 6;
    int bx = blockIdx.x;
    int cl = lane & 15, kg = lane >> 4;
    int kbase = kg * 8;

    // --- build B fragments for 2 col-tiles, with fused normalization ---
    bf16x8 bF[2][4];
    for (int ct2 = 0; ct2 < 2; ct2++) {
        int c0 = bx * 128 + w * 32 + ct2 * 16 + cl;   // output col
        float x[4][8];
        float ss = 0.f;
        if (c0 < NCOL) {
            const float* e = emb + (size_t)(c0 + 1) * 128 + kbase;
            for (int kk = 0; kk < 4; kk++) {
                float4 v0 = *(const float4*)(e + kk * 32);
                float4 v1 = *(const float4*)(e + kk * 32 + 4);
                x[kk][0] = v0.x; x[kk][1] = v0.y; x[kk][2] = v0.z; x[kk][3] = v0.w;
                x[kk][4] = v1.x; x[kk][5] = v1.y; x[kk][6] = v1.z; x[kk][7] = v1.w;
                for (int j = 0; j < 8; j++) ss += x[kk][j] * x[kk][j];
            }
        } else {
            for (int kk = 0; kk < 4; kk++)
                for (int j = 0; j < 8; j++) x[kk][j] = 0.f;
        }
        ss += __shfl_xor(ss, 16);
        ss += __shfl_xor(ss, 32);          // full-column sum across the 4 k-groups
        float inv = 1.f / (sqrtf(ss) + 1e-12f);
        for (int kk = 0; kk < 4; kk++) {
            bf16x8 f;
            for (int j = 0; j < 8; j++) f[j] = f2bf(x[kk][j] * inv);
            bF[ct2][kk] = f;
        }
    }

    int cend = NCOL - bx * 128;
    if (cend > 128) cend = 128;

    // --- loop over 32 row-tiles of A (512 rows) ---
    for (int rt = 0; rt < 32; rt++) {
        bf16x8 aF[4];
        const short* Arow = a_bf + ((size_t)(rt * 16 + cl)) * 128 + kbase;
        for (int kk = 0; kk < 4; kk++) aF[kk] = *(const bf16x8*)(Arow + kk * 32);
        f32x4 acc0 = {0.f, 0.f, 0.f, 0.f}, acc1 = {0.f, 0.f, 0.f, 0.f};
        for (int kk = 0; kk < 4; kk++) {
            acc0 = __builtin_amdgcn_mfma_f32_16x16x32_bf16(aF[kk], bF[0][kk], acc0, 0, 0, 0);
            acc1 = __builtin_amdgcn_mfma_f32_16x16x32_bf16(aF[kk], bF[1][kk], acc1, 0, 0, 0);
        }
        __syncthreads();   // previous store-phase done reading LDS
        for (int rg = 0; rg < 4; rg++) {
            lds_c[kg * 4 + rg][w * 32 + cl]      = 12.f * acc0[rg];
            lds_c[kg * 4 + rg][w * 32 + 16 + cl] = 12.f * acc1[rg];
        }
        __syncthreads();
        // coalesced store: wave w handles rows p*4 + w, 64 lanes contiguous
        for (int p = 0; p < 4; p++) {
            int row = p * 4 + w;
            size_t gr = (size_t)(rt * 16 + row) * NCOL + (size_t)bx * 128;
            for (int q = 0; q < 2; q++) {
                int col = q * 64 + lane;
                if (col < cend) out[gr + col] = lds_c[row][col];
            }
        }
    }
}

extern "C" void kernel_launch(void* const* d_in, const int* in_sizes, int n_in,
                              void* d_out, int out_size, void* d_ws, size_t ws_size,
                              hipStream_t stream) {
    const float* hidden     = (const float*)d_in[0];
    const float* hidden0    = (const float*)d_in[1];
    const int*   mask       = (const int*)d_in[2];
    const float* s          = (const float*)d_in[3];
    const float* emb        = (const float*)d_in[4];
    const float* attn_in_w  = (const float*)d_in[5];
    const float* attn_in_b  = (const float*)d_in[6];
    const float* attn_out_w = (const float*)d_in[7];
    const float* attn_out_b = (const float*)d_in[8];
    const float* w_zero     = (const float*)d_in[9];
    const float* b_zero     = (const float*)d_in[10];
    const float* w_one      = (const float*)d_in[11];
    const float* b_one      = (const float*)d_in[12];
    const float* w_two      = (const float*)d_in[13];
    const float* b_two      = (const float*)d_in[14];
    const float* w_three    = (const float*)d_in[15];
    const float* w_gate     = (const float*)d_in[16];
    const float* w_trans    = (const float*)d_in[17];
    const float* b_trans    = (const float*)d_in[18];
    float* out = (float*)d_out;

    char* p = (char*)d_ws;
    float* ht0    = (float*)p; p += (size_t)B_SZ * 128 * 4;
    float* q01    = (float*)p; p += (size_t)B_SZ * 128 * 4;
    float* alphaL = (float*)p; p += (size_t)B_SZ * L_SZ * 8 * 4;
    short* a_bf   = (short*)p; p += (size_t)B_SZ * 128 * 2;
    short* Wkv    = (short*)p; p += (size_t)256 * 128 * 2;
    short* W2     = (short*)p; p += (size_t)128 * 128 * 2;
    float* wqT    = (float*)p; p += (size_t)128 * 128 * 4;
    float* woT    = (float*)p; p += (size_t)128 * 128 * 4;
    float* w0T    = (float*)p; p += (size_t)128 * 128 * 4;
    float* w1T    = (float*)p; p += (size_t)128 * 128 * 4;
    float* wtT    = (float*)p; p += (size_t)256 * 128 * 4;
    short* g_bf   = (short*)p; p += (size_t)M_ROWS * 128 * 2;
    short* kv     = (short*)p; p += (size_t)M_ROWS * 256 * 2;

    k_prep<<<128, 256, 0, stream>>>(attn_in_w, w_two, attn_out_w, w_zero, w_one, w_trans,
                                    Wkv, W2, wqT, woT, w0T, w1T, wtT);
    k_gate<<<M_ROWS, 128, 0, stream>>>(hidden, hidden0, w_gate, g_bf);
    k_gemm_kv<<<M_ROWS / 64, 256, 0, stream>>>(hidden, Wkv, attn_in_b, kv);
    k_attn<<<B_SZ, 128, 0, stream>>>(hidden, mask, s, wqT, attn_in_b, kv,
                                     woT, attn_out_b, w0T, b_zero, w1T, b_one, ht0, q01);
    k_gemm_q2_alpha<<<M_ROWS / 64, 256, 0, stream>>>(g_bf, W2, b_two, q01, w_three, alphaL);
    k_alpha_a<<<B_SZ, 128, 0, stream>>>(alphaL, mask, g_bf, ht0, wtT, b_trans, a_bf);
    k_final<<<(NCOL + 127) / 128, 256, 0, stream>>>(a_bf, emb, out);
}